// Round 4
// baseline (2854.231 us; speedup 1.0000x reference)
//
#include <hip/hip_runtime.h>
#include <math.h>

#define T_N   1000
#define L_N   1024
#define N_B   64
#define PAD   256          // zero pad (words) covering max window under-run
#define LOG2E 1.4426950408889634f
#define LN2   0.6931471805599453f
#define DT_F  0.01f

// ---------------- Kernel A: sinr[n,i] = y_ii / (y_ij + 1) ----------------
__global__ __launch_bounds__(256) void sinr_kernel(const float* __restrict__ powers,
                                                   const float* __restrict__ pathloss,
                                                   float* __restrict__ sinr) {
    __shared__ float row[L_N];
    const int i   = blockIdx.x;
    const int tid = threadIdx.x;
    for (int j = tid; j < L_N; j += 256) row[j] = pathloss[i * L_N + j];
    __syncthreads();
    const float pii  = row[i];
    const int   wv   = tid >> 6;
    const int   lane = tid & 63;
    for (int n = wv * 16; n < wv * 16 + 16; ++n) {
        const float* pr = powers + n * L_N;
        float part = 0.f;
        #pragma unroll
        for (int k = 0; k < L_N / 64; ++k)
            part += row[lane + 64 * k] * pr[lane + 64 * k];
        #pragma unroll
        for (int off = 32; off > 0; off >>= 1)
            part += __shfl_down(part, off, 64);
        if (lane == 0) {
            float yii = pii * pr[i];
            sinr[n * L_N + i] = yii / (part - yii + 1.0f);
        }
    }
}

// acc A (out quad q) += window(H = Q quad(q-c), L = Q quad(q-c-1)) x R = r quad c
#define CH(A, H, L, R) do {                                                                \
    A.x = fmaf((H).x,(R).x,A.x); A.y = fmaf((H).y,(R).x,A.y);                              \
    A.z = fmaf((H).z,(R).x,A.z); A.w = fmaf((H).w,(R).x,A.w);                              \
    A.x = fmaf((L).w,(R).y,A.x); A.y = fmaf((H).x,(R).y,A.y);                              \
    A.z = fmaf((H).y,(R).y,A.z); A.w = fmaf((H).z,(R).y,A.w);                              \
    A.x = fmaf((L).z,(R).z,A.x); A.y = fmaf((L).w,(R).z,A.y);                              \
    A.z = fmaf((H).x,(R).z,A.z); A.w = fmaf((H).y,(R).z,A.w);                              \
    A.x = fmaf((L).y,(R).w,A.x); A.y = fmaf((L).z,(R).w,A.y);                              \
    A.z = fmaf((L).w,(R).w,A.z); A.w = fmaf((H).x,(R).w,A.w);                              \
} while (0)

// ---------------- Kernel B: 4 waves per link, 1 output quad per lane ----------------
__global__ __launch_bounds__(256, 4) void scan_kernel(const float* __restrict__ powers,
                                                      const float* __restrict__ sinr,
                                                      float* __restrict__ partial) {
    __shared__ __align__(16) float p2t[1024];
    __shared__ __align__(16) float Qb[2][PAD + 1024];
    __shared__ __align__(16) float rr[1024];
    __shared__ float sv[N_B];
    __shared__ float tails[N_B];

    const int l    = blockIdx.x;
    const int tid  = threadIdx.x;          // 0..255
    const int wv   = tid >> 6;             // wave 0..3
    const int lane = tid & 63;

    if (tid < N_B) sv[tid] = sinr[tid * L_N + l];
    // 2^t table: one quad per thread
    {
        float4 v;
        v.x = exp2f(0.01f * (float)(4 * tid + 0));
        v.y = exp2f(0.01f * (float)(4 * tid + 1));
        v.z = exp2f(0.01f * (float)(4 * tid + 2));
        v.w = exp2f(0.01f * (float)(4 * tid + 3));
        *(float4*)&p2t[4 * tid] = v;
    }
    // zero pads of both Q buffers (words 0..PAD-1)
    if (tid < PAD / 4) {
        float4 z = make_float4(0.f, 0.f, 0.f, 0.f);
        *(float4*)&Qb[0][4 * tid] = z;
        *(float4*)&Qb[1][4 * tid] = z;
    }
    __syncthreads();

    // Q1[j] = 1 - exp2((1 - 2^t_j) * s0 * log2e), zero for j >= 1000
    {
        const float s0l = sv[0] * LOG2E;
        float4 p = *(const float4*)&p2t[4 * tid];
        float4 v = make_float4(0.f, 0.f, 0.f, 0.f);
        if (tid < 250) {
            v.x = 1.f - exp2f((1.f - p.x) * s0l);
            v.y = 1.f - exp2f((1.f - p.y) * s0l);
            v.z = 1.f - exp2f((1.f - p.z) * s0l);
            v.w = 1.f - exp2f((1.f - p.w) * s0l);
        }
        *(float4*)&Qb[0][PAD + 4 * tid] = v;
        if (tid == 249) tails[0] = v.w;    // Q1[999]
    }
    __syncthreads();

    const int q    = 64 * wv + lane;       // this lane's output quad (0..255)
    const int ob   = PAD + 4 * q;          // word index of output quad
    const int trip = 64 * (wv + 1);        // wave-uniform tap-quad count

    int cb = 0;
    for (int n = 1; n < N_B; ++n) {
        // r[d] = DT * q_n[T-1-d]; r[d >= 1000] = 0   (one quad per thread)
        {
            const float s    = sv[n];
            const float sl   = s * LOG2E;
            const float smul = s * LN2 * DT_F;
            const int dbase  = 4 * tid;
            float4 o = make_float4(0.f, 0.f, 0.f, 0.f);
            if (dbase < T_N) {
                float4 p = *(const float4*)&p2t[996 - dbase];
                o.x = smul * p.w * exp2f((1.f - p.w) * sl);
                o.y = smul * p.z * exp2f((1.f - p.z) * sl);
                o.z = smul * p.y * exp2f((1.f - p.y) * sl);
                o.w = smul * p.x * exp2f((1.f - p.x) * sl);
            }
            *(float4*)&rr[4 * tid] = o;
        }
        __syncthreads();

        const float*  cur = Qb[cb];
        float*        nxt = Qb[cb ^ 1];
        const float4* r4  = (const float4*)rr;

        float4 A  = make_float4(0.f, 0.f, 0.f, 0.f);
        float4 wh = *(const float4*)&cur[ob];          // quad q
        #pragma unroll 4
        for (int c = 0; c < trip; ++c) {
            float4 wl = *(const float4*)&cur[ob - 4 * c - 4];   // quad q-c-1 (pad-safe)
            float4 rq = r4[c];
            CH(A, wh, wl, rq);
            wh = wl;
        }

        *(float4*)&nxt[ob] = A;
        if (tid == 249) tails[n] = A.w;    // output 999 (quad 249, elem 3)
        __syncthreads();
        cb ^= 1;
    }

    // per-link loss contribution (first wave only)
    if (tid < N_B) {
        float tl   = tails[tid];
        float term = (tid < N_B - 1) ? tl * (powers[(tid + 1) * L_N + l] + 1.0f) : tl;
        if (tid == 0) term += powers[l] + 1.0f;
        #pragma unroll
        for (int off = 32; off > 0; off >>= 1) term += __shfl_down(term, off, 64);
        if (tid == 0) partial[l] = term;
    }
}

// ---------------- Kernel C: final deterministic reduction ----------------
__global__ __launch_bounds__(256) void reduce_kernel(const float* __restrict__ partial,
                                                     float* __restrict__ out) {
    __shared__ float red[4];
    const int tid = threadIdx.x;
    float v = partial[tid] + partial[tid + 256] + partial[tid + 512] + partial[tid + 768];
    #pragma unroll
    for (int off = 32; off > 0; off >>= 1) v += __shfl_down(v, off, 64);
    if ((tid & 63) == 0) red[tid >> 6] = v;
    __syncthreads();
    if (tid == 0) out[0] = red[0] + red[1] + red[2] + red[3];
}

extern "C" void kernel_launch(void* const* d_in, const int* in_sizes, int n_in,
                              void* d_out, int out_size, void* d_ws, size_t ws_size,
                              hipStream_t stream) {
    const float* powers   = (const float*)d_in[0];
    const float* pathloss = (const float*)d_in[1];
    float* sinr    = (float*)d_ws;            // 64*1024 floats
    float* partial = sinr + N_B * L_N;        // 1024 floats

    sinr_kernel<<<dim3(L_N), dim3(256), 0, stream>>>(powers, pathloss, sinr);
    scan_kernel<<<dim3(L_N), dim3(256), 0, stream>>>(powers, sinr, partial);
    reduce_kernel<<<dim3(1), dim3(256), 0, stream>>>(partial, (float*)d_out);
}

// Round 5
// 1289.883 us; speedup vs baseline: 2.2128x; 2.2128x over previous
//
#include <hip/hip_runtime.h>
#include <math.h>

#define T_N   1000
#define L_N   1024
#define N_B   64
#define PADQ  72           // zero-pad quads at the head of each parity array
#define NQ    128          // live quads per parity array (256 quads total)
#define LOG2E 1.4426950408889634f
#define LN2   0.6931471805599453f
#define DT_F  0.01f

// ---------------- Kernel A: sinr[n,i] = y_ii / (y_ij + 1) ----------------
__global__ __launch_bounds__(256) void sinr_kernel(const float* __restrict__ powers,
                                                   const float* __restrict__ pathloss,
                                                   float* __restrict__ sinr) {
    __shared__ float row[L_N];
    const int i   = blockIdx.x;
    const int tid = threadIdx.x;
    for (int j = tid; j < L_N; j += 256) row[j] = pathloss[i * L_N + j];
    __syncthreads();
    const float pii  = row[i];
    const int   wv   = tid >> 6;
    const int   lane = tid & 63;
    for (int n = wv * 16; n < wv * 16 + 16; ++n) {
        const float* pr = powers + n * L_N;
        float part = 0.f;
        #pragma unroll
        for (int k = 0; k < L_N / 64; ++k)
            part += row[lane + 64 * k] * pr[lane + 64 * k];
        #pragma unroll
        for (int off = 32; off > 0; off >>= 1)
            part += __shfl_down(part, off, 64);
        if (lane == 0) {
            float yii = pii * pr[i];
            sinr[n * L_N + i] = yii / (part - yii + 1.0f);
        }
    }
}

// acc A (out quad q) += window(H = Q quad(q-c), L = Q quad(q-c-1)) x R = r quad c
#define CH(A, H, L, R) do {                                                                \
    A.x = fmaf((H).x,(R).x,A.x); A.y = fmaf((H).y,(R).x,A.y);                              \
    A.z = fmaf((H).z,(R).x,A.z); A.w = fmaf((H).w,(R).x,A.w);                              \
    A.x = fmaf((L).w,(R).y,A.x); A.y = fmaf((H).x,(R).y,A.y);                              \
    A.z = fmaf((H).y,(R).y,A.z); A.w = fmaf((H).z,(R).y,A.w);                              \
    A.x = fmaf((L).z,(R).z,A.x); A.y = fmaf((L).w,(R).z,A.y);                              \
    A.z = fmaf((H).x,(R).z,A.z); A.w = fmaf((H).y,(R).z,A.w);                              \
    A.x = fmaf((L).y,(R).w,A.x); A.y = fmaf((L).z,(R).w,A.y);                              \
    A.z = fmaf((L).w,(R).w,A.z); A.w = fmaf((H).x,(R).w,A.w);                              \
} while (0)

// ---------------- Kernel B: 1 link/block, 2 waves, parity-split Q ----------------
// Lane owns out-quads (B+2l, B+2l+1); even quads live in QE, odd in QO, so the
// sliding window needs ONE new quad per tap-quad, alternating arrays, and every
// LDS read is contiguous 16B-stride across lanes with linear addressing.
__global__ __launch_bounds__(128) void scan_kernel(const float* __restrict__ powers,
                                                   const float* __restrict__ sinr,
                                                   float* __restrict__ partial) {
    __shared__ __align__(16) float p2t[1024];
    __shared__ __align__(16) float QE[2][(PADQ + NQ) * 4];
    __shared__ __align__(16) float QO[2][(PADQ + NQ) * 4];
    __shared__ __align__(16) float rr[1024];
    __shared__ float sv[N_B];
    __shared__ float tails[N_B];

    const int l    = blockIdx.x;
    const int tid  = threadIdx.x;                       // 0..127
    const int lane = tid & 63;
    const int wr   = ((tid >> 6) + blockIdx.x) & 1;     // role: 0 light, 1 heavy

    // 2^t table: 128 threads x 2 quads
    #pragma unroll
    for (int m = 0; m < 2; ++m) {
        const int jq = tid + 128 * m;
        float4 v;
        v.x = exp2f(0.01f * (float)(4 * jq + 0));
        v.y = exp2f(0.01f * (float)(4 * jq + 1));
        v.z = exp2f(0.01f * (float)(4 * jq + 2));
        v.w = exp2f(0.01f * (float)(4 * jq + 3));
        *(float4*)&p2t[4 * jq] = v;
    }
    if (tid < N_B) sv[tid] = sinr[tid * L_N + l];
    if (tid < PADQ) {
        const float4 z = make_float4(0.f, 0.f, 0.f, 0.f);
        *(float4*)&QE[0][4 * tid] = z;  *(float4*)&QE[1][4 * tid] = z;
        *(float4*)&QO[0][4 * tid] = z;  *(float4*)&QO[1][4 * tid] = z;
    }
    __syncthreads();

    // Q1 init: thread t -> quads 2t (QE) and 2t+1 (QO); zero for elements >= 1000
    {
        const float s0l = sv[0] * LOG2E;
        float4 e = make_float4(0.f, 0.f, 0.f, 0.f);
        float4 o = make_float4(0.f, 0.f, 0.f, 0.f);
        if (tid < 125) {
            float4 pe_ = *(const float4*)&p2t[8 * tid];
            float4 po_ = *(const float4*)&p2t[8 * tid + 4];
            e.x = 1.f - exp2f((1.f - pe_.x) * s0l);
            e.y = 1.f - exp2f((1.f - pe_.y) * s0l);
            e.z = 1.f - exp2f((1.f - pe_.z) * s0l);
            e.w = 1.f - exp2f((1.f - pe_.w) * s0l);
            o.x = 1.f - exp2f((1.f - po_.x) * s0l);
            o.y = 1.f - exp2f((1.f - po_.y) * s0l);
            o.z = 1.f - exp2f((1.f - po_.z) * s0l);
            o.w = 1.f - exp2f((1.f - po_.w) * s0l);
        }
        *(float4*)&QE[0][(PADQ + tid) * 4] = e;
        *(float4*)&QO[0][(PADQ + tid) * 4] = o;
        if (tid == 124) tails[0] = o.w;                 // Q1[999]
    }
    __syncthreads();

    const int Bh     = 64 * wr;                         // B/2 (B = 128*wr)
    const int npairs = wr ? 125 : 64;                   // tap-quads / 2
    const int wq     = PADQ + Bh + lane;                // lane's quad slot in QE/QO

    int cb = 0;
    for (int n = 1; n < N_B; ++n) {
        // taps r[d] = DT * q_n[999-d]; zero for d >= 1000
        {
            const float s    = sv[n];
            const float sl   = s * LOG2E;
            const float smul = s * LN2 * DT_F;
            #pragma unroll
            for (int m = 0; m < 2; ++m) {
                const int c     = tid + 128 * m;
                const int dbase = 4 * c;
                float4 o = make_float4(0.f, 0.f, 0.f, 0.f);
                if (dbase < T_N) {
                    float4 p = *(const float4*)&p2t[996 - dbase];
                    o.x = smul * p.w * exp2f((1.f - p.w) * sl);
                    o.y = smul * p.z * exp2f((1.f - p.z) * sl);
                    o.z = smul * p.y * exp2f((1.f - p.y) * sl);
                    o.w = smul * p.x * exp2f((1.f - p.x) * sl);
                }
                *(float4*)&rr[4 * c] = o;
            }
        }
        __syncthreads();

        const float* QEc = QE[cb];
        const float* QOc = QO[cb];
        float*       QEn = QE[cb ^ 1];
        float*       QOn = QO[cb ^ 1];

        float4 aA = make_float4(0.f, 0.f, 0.f, 0.f);    // out quad B+2l   (even)
        float4 aB = make_float4(0.f, 0.f, 0.f, 0.f);    // out quad B+2l+1 (odd)

        float4 hi  = *(const float4*)&QOc[4 * wq];       // quad B+2l+1
        float4 mid = *(const float4*)&QEc[4 * wq];       // quad B+2l
        float4 lo  = *(const float4*)&QOc[4 * (wq - 1)]; // quad B+2l-1
        int pe = 4 * (wq - 1);                           // next even window quad
        int po = 4 * (wq - 2);                           // next odd window quad

        #pragma unroll 2
        for (int p = 0; p < npairs; ++p) {
            float4 N1 = *(const float4*)&QEc[pe]; pe -= 4;
            float4 N2 = *(const float4*)&QOc[po]; po -= 4;
            float4 r0 = *(const float4*)&rr[8 * p];
            float4 r1 = *(const float4*)&rr[8 * p + 4];
            CH(aB, hi,  mid, r0);    // c = 2p   on odd quad
            CH(aA, mid, lo,  r0);    // c = 2p   on even quad
            CH(aB, mid, lo,  r1);    // c = 2p+1 on odd quad
            CH(aA, lo,  N1,  r1);    // c = 2p+1 on even quad
            hi = lo; mid = N1; lo = N2;
        }

        *(float4*)&QEn[4 * wq] = aA;
        *(float4*)&QOn[4 * wq] = aB;
        if (wr == 1 && lane == 60) tails[n] = aB.w;      // out quad 249, elem 3 = out[999]
        __syncthreads();
        cb ^= 1;
    }

    // per-link loss contribution (wave 0 of the block)
    if (tid < N_B) {
        float tl   = tails[tid];
        float term = (tid < N_B - 1) ? tl * (powers[(tid + 1) * L_N + l] + 1.0f) : tl;
        if (tid == 0) term += powers[l] + 1.0f;
        #pragma unroll
        for (int off = 32; off > 0; off >>= 1) term += __shfl_down(term, off, 64);
        if (tid == 0) partial[l] = term;
    }
}

// ---------------- Kernel C: final deterministic reduction ----------------
__global__ __launch_bounds__(256) void reduce_kernel(const float* __restrict__ partial,
                                                     float* __restrict__ out) {
    __shared__ float red[4];
    const int tid = threadIdx.x;
    float v = partial[tid] + partial[tid + 256] + partial[tid + 512] + partial[tid + 768];
    #pragma unroll
    for (int off = 32; off > 0; off >>= 1) v += __shfl_down(v, off, 64);
    if ((tid & 63) == 0) red[tid >> 6] = v;
    __syncthreads();
    if (tid == 0) out[0] = red[0] + red[1] + red[2] + red[3];
}

extern "C" void kernel_launch(void* const* d_in, const int* in_sizes, int n_in,
                              void* d_out, int out_size, void* d_ws, size_t ws_size,
                              hipStream_t stream) {
    const float* powers   = (const float*)d_in[0];
    const float* pathloss = (const float*)d_in[1];
    float* sinr    = (float*)d_ws;            // 64*1024 floats
    float* partial = sinr + N_B * L_N;        // 1024 floats

    sinr_kernel<<<dim3(L_N), dim3(256), 0, stream>>>(powers, pathloss, sinr);
    scan_kernel<<<dim3(L_N), dim3(128), 0, stream>>>(powers, sinr, partial);
    reduce_kernel<<<dim3(1), dim3(256), 0, stream>>>(partial, (float*)d_out);
}